// Round 16
// baseline (3257.979 us; speedup 1.0000x reference)
//
#include <hip/hip_runtime.h>
#include <cstddef>

// Problem constants
#define Bsz  4096
#define Sseq 16
#define Gdim 128
#define Edim 256
#define Hdim 512
#define H4   2048
#define Psteps 16
#define BK   16

typedef short bfrag8 __attribute__((ext_vector_type(8)));   // 8 bf16 (4 VGPR)
typedef float f32x4  __attribute__((ext_vector_type(4)));   // MFMA acc

// Exact 3-way bf16 split of fp32 (truncation; residuals exactly representable:
// 24 mantissa bits = 8+8+8). a == hi+mid+lo exactly (normal range).
__device__ __forceinline__ void split3(float f, unsigned short& h,
                                       unsigned short& m, unsigned short& l) {
    unsigned u = __float_as_uint(f);
    h = (unsigned short)(u >> 16);
    float r1 = f - __uint_as_float(u & 0xffff0000u);
    unsigned u1 = __float_as_uint(r1);
    m = (unsigned short)(u1 >> 16);
    float r2 = r1 - __uint_as_float(u1 & 0xffff0000u);
    l = (unsigned short)(__float_as_uint(r2) >> 16);
}

// ---------------------------------------------------------------------------
// Fold kernel: gate-interleaved (row c = j*4+gate) weight prep, emitting
// bf16 hi/mid/lo planes for the MFMA path. Wih rows staged in LDS first
// (coalesced), e-loop reads LDS broadcasts -- same sequential FMA order.
// ---------------------------------------------------------------------------
__global__ void fold_kernel(const float* __restrict__ encWih,
                            const float* __restrict__ encWhh,
                            const float* __restrict__ enc_b,
                            const float* __restrict__ decWih,
                            const float* __restrict__ decWhh,
                            const float* __restrict__ dec_b,
                            const float* __restrict__ embW,
                            const float* __restrict__ dec0,
                            unsigned short* __restrict__ encEh,
                            unsigned short* __restrict__ encEm,
                            unsigned short* __restrict__ encEl,
                            unsigned short* __restrict__ encWh,
                            unsigned short* __restrict__ encWm,
                            unsigned short* __restrict__ encWl,
                            unsigned short* __restrict__ decEh,
                            unsigned short* __restrict__ decEm,
                            unsigned short* __restrict__ decEl,
                            unsigned short* __restrict__ decWh,
                            unsigned short* __restrict__ decWm,
                            unsigned short* __restrict__ decWl,
                            float* __restrict__ encBI, float* __restrict__ decBI,
                            float* __restrict__ v0bI) {
    __shared__ float rE[Edim], rD[Edim];
    const int o = blockIdx.x;            // original row 0..2047 (gate*512 + j)
    const int gate = o >> 9, j = o & 511;
    const int c = j * 4 + gate;          // interleaved row
    const int g = threadIdx.x;           // 0..127
    rE[g]        = encWih[(size_t)o * Edim + g];
    rE[g + Gdim] = encWih[(size_t)o * Edim + g + Gdim];
    rD[g]        = decWih[(size_t)o * Edim + g];
    rD[g + Gdim] = decWih[(size_t)o * Edim + g + Gdim];
    __syncthreads();

    float se = 0.f, sd = 0.f;
#pragma unroll 8
    for (int e = 0; e < Edim; ++e) {
        float w = embW[e * Gdim + g];
        se += rE[e] * w;                 // same sequential order as before
        sd += rD[e] * w;
    }
    unsigned short h, m, l;
    split3(se, h, m, l);
    encEh[(size_t)c * Gdim + g] = h; encEm[(size_t)c * Gdim + g] = m;
    encEl[(size_t)c * Gdim + g] = l;
    split3(sd, h, m, l);
    decEh[(size_t)c * Gdim + g] = h; decEm[(size_t)c * Gdim + g] = m;
    decEl[(size_t)c * Gdim + g] = l;
    for (int k = g; k < Hdim; k += Gdim) {
        split3(encWhh[(size_t)o * Hdim + k], h, m, l);
        encWh[(size_t)c * Hdim + k] = h; encWm[(size_t)c * Hdim + k] = m;
        encWl[(size_t)c * Hdim + k] = l;
        split3(decWhh[(size_t)o * Hdim + k], h, m, l);
        decWh[(size_t)c * Hdim + k] = h; decWm[(size_t)c * Hdim + k] = m;
        decWl[(size_t)c * Hdim + k] = l;
    }
    if (g == 0) {
        encBI[c] = enc_b[o];
        decBI[c] = dec_b[o];
        float s = dec_b[o];
        for (int e = 0; e < Edim; ++e) s += rD[e] * dec0[e];  // same order
        v0bI[c] = s;
    }
}

// ---------------------------------------------------------------------------
// Plane prep for the projection weights (Wref2, Wq2): row-major hi/mid/lo
// bf16 planes, 512x512 each. grid (512, 2).
// ---------------------------------------------------------------------------
__global__ __launch_bounds__(256) void fold_proj(
    const float* __restrict__ Wr, const float* __restrict__ Wq,
    unsigned short* __restrict__ rWh, unsigned short* __restrict__ rWm,
    unsigned short* __restrict__ rWl,
    unsigned short* __restrict__ qWh, unsigned short* __restrict__ qWm,
    unsigned short* __restrict__ qWl) {
    const int o = blockIdx.x;
    const float* src = blockIdx.y ? Wq : Wr;
    unsigned short* ph = blockIdx.y ? qWh : rWh;
    unsigned short* pm = blockIdx.y ? qWm : rWm;
    unsigned short* pl = blockIdx.y ? qWl : rWl;
    for (int k = threadIdx.x; k < Hdim; k += 256) {
        unsigned short h, m, l;
        split3(src[(size_t)o * Hdim + k], h, m, l);
        ph[(size_t)o * Hdim + k] = h;
        pm[(size_t)o * Hdim + k] = m;
        pl[(size_t)o * Hdim + k] = l;
    }
}

// ---------------------------------------------------------------------------
// MFMA gates GEMM + fused LSTM epilogue, fp32-exact via bf16x6 emulation.
// (round-15 version, verbatim: 128m x 128n block, 8 waves, wave = 16m x
// 128n, grid (32,16)=512, weight LDS double-buffer 48 KB, direct act loads.
// Best measured config: ~69.7us, MfmaUtil 38% = the 2-barrier ceiling.)
// ---------------------------------------------------------------------------
__global__ __launch_bounds__(512) void gates_mfma(
    const unsigned short* __restrict__ Wh1, const unsigned short* __restrict__ Wm1,
    const unsigned short* __restrict__ Wl1, int K1,
    const float* __restrict__ X, int ldx,
    const int* __restrict__ gather, int gmul,
    const unsigned short* __restrict__ Wh2, const unsigned short* __restrict__ Wm2,
    const unsigned short* __restrict__ Wl2, int K2,
    const float* __restrict__ Hin,
    const float* __restrict__ biasI,
    const float* __restrict__ c_in, float* __restrict__ h_out,
    float* __restrict__ c_out, int czero)
{
    __shared__ __align__(16) unsigned short wlds[2][3 * 4096]; // 48 KB

    const int tid = threadIdx.x;                 // 0..511
    const int wv = tid >> 6, lane = tid & 63;    // 8 waves
    const int lm = lane & 15, quad = lane >> 4;
    const int c0 = blockIdx.y * 128;             // block n-panel base row
    const int mB0 = blockIdx.x * 128;            // block batch base (128 rows)

    const int mrow = mB0 + wv * 16 + lm;         // this lane's act/output row

    // ---- weight staging: 128 rows x 4 units x 3 planes; 512 thr, 1 unit
    //      per thread per plane. Wave wv stages rows wv*16..wv*16+15.
    const int srow = wv * 16 + (lane >> 2);
    const int sqs = (lane & 3) ^ ((srow >> 1) & 3);   // pre-swizzled src unit
    const size_t roff1 = (size_t)(c0 + srow) * K1 + (size_t)(sqs * 8);
    const size_t roff2 = (size_t)(c0 + srow) * K2 + (size_t)(sqs * 8);

    // ---- act pointers (direct global; wave rows are private, no dup) ----
    const float* xr = nullptr;
    const float* hr = nullptr;
    if (X) {
        size_t off = (size_t)mrow * ldx;
        if (gather) off += (size_t)gather[mrow] * gmul;
        xr = X + off;
    }
    if (Hin) hr = Hin + (size_t)mrow * K2;

    // ---- weight ds_read fragment offsets (ushort units), 8 n-tiles ----
    int boffW[8];
#pragma unroll
    for (int tn = 0; tn < 8; ++tn) {
        const int r = tn * 16 + lm;
        boffW[tn] = r * 32 + ((quad ^ ((r >> 1) & 3)) * 8);
    }

    auto stage = [&](int kcN, int buf) {
        const bool nX = kcN < K1;
        const int kb = nX ? kcN : kcN - K1;
        unsigned short* lb = &wlds[buf][wv * 512];
        const unsigned short* gh = (nX ? Wh1 + roff1 : Wh2 + roff2) + kb;
        const unsigned short* gm = (nX ? Wm1 + roff1 : Wm2 + roff2) + kb;
        const unsigned short* gl = (nX ? Wl1 + roff1 : Wl2 + roff2) + kb;
        __builtin_amdgcn_global_load_lds(
            (const __attribute__((address_space(1))) void*)gh,
            (__attribute__((address_space(3))) void*)(lb), 16, 0, 0);
        __builtin_amdgcn_global_load_lds(
            (const __attribute__((address_space(1))) void*)gm,
            (__attribute__((address_space(3))) void*)(lb + 4096), 16, 0, 0);
        __builtin_amdgcn_global_load_lds(
            (const __attribute__((address_space(1))) void*)gl,
            (__attribute__((address_space(3))) void*)(lb + 8192), 16, 0, 0);
    };

    f32x4 acc[8];
#pragma unroll
    for (int i = 0; i < 8; ++i) acc[i] = (f32x4){0.f, 0.f, 0.f, 0.f};

    const int KT = K1 + K2;
    stage(0, 0);
    int cur = 0;

    for (int kc = 0; kc < KT; kc += 32) {
        __syncthreads();                       // drains staged loads for buf[cur]
        if (kc + 32 < KT) stage(kc + 32, cur ^ 1);

        const bool inX = kc < K1;
        const int kk = (inX ? kc : kc - K1) + quad * 8;

        // this wave's single act fragment: direct global, split3 in VALU
        const float* p = (inX ? xr : hr) + kk;
        float a8[8];
        *(float4*)&a8[0] = *(const float4*)(p);
        *(float4*)&a8[4] = *(const float4*)(p + 4);
        bfrag8 bh, bm, bl;
#pragma unroll
        for (int j = 0; j < 8; ++j) {
            unsigned short h, m, l;
            split3(a8[j], h, m, l);
            bh[j] = (short)h; bm[j] = (short)m; bl[j] = (short)l;
        }

        const unsigned short* bufp = wlds[cur];
#pragma unroll
        for (int hh = 0; hh < 2; ++hh) {
            bfrag8 ah[4], am4[4], al[4];
#pragma unroll
            for (int t = 0; t < 4; ++t) {
                const int tn = hh * 4 + t;
                ah[t]  = *(const bfrag8*)(bufp + boffW[tn]);
                am4[t] = *(const bfrag8*)(bufp + 4096 + boffW[tn]);
                al[t]  = *(const bfrag8*)(bufp + 8192 + boffW[tn]);
            }
#pragma unroll
            for (int t = 0; t < 4; ++t) {
                const int tn = hh * 4 + t;
                f32x4 c = acc[tn];
                c = __builtin_amdgcn_mfma_f32_16x16x32_bf16(ah[t], bl, c, 0, 0, 0);
                c = __builtin_amdgcn_mfma_f32_16x16x32_bf16(al[t], bh, c, 0, 0, 0);
                c = __builtin_amdgcn_mfma_f32_16x16x32_bf16(am4[t], bm, c, 0, 0, 0);
                c = __builtin_amdgcn_mfma_f32_16x16x32_bf16(ah[t], bm, c, 0, 0, 0);
                c = __builtin_amdgcn_mfma_f32_16x16x32_bf16(am4[t], bh, c, 0, 0, 0);
                c = __builtin_amdgcn_mfma_f32_16x16x32_bf16(ah[t], bh, c, 0, 0, 0);
                acc[tn] = c;
            }
        }
        cur ^= 1;
    }

    // fused LSTM epilogue: lane's 4 acc regs = gates i,f,g,o of unit j
#pragma unroll
    for (int tn = 0; tn < 8; ++tn) {
        const int nb = c0 + tn * 16 + quad * 4;
        float4 bb = *(const float4*)(biasI + nb);
        const int j = nb >> 2;
        const size_t idx = (size_t)mrow * Hdim + j;
        float gi = acc[tn][0] + bb.x;
        float gf = acc[tn][1] + bb.y;
        float gg = acc[tn][2] + bb.z;
        float go = acc[tn][3] + bb.w;
        float si = 1.f / (1.f + expf(-gi));
        float sf = 1.f / (1.f + expf(-gf));
        float so = 1.f / (1.f + expf(-go));
        float co = czero ? 0.f : c_in[idx];
        float cn = si * tanhf(gg) + sf * co;
        c_out[idx] = cn;
        h_out[idx] = so * tanhf(cn);
    }
}

// ---------------------------------------------------------------------------
// MFMA projection GEMM: C[m] = A[m] @ W^T + bias (W via bf16x6 planes,
// K=512). Row-independent, so it runs either per-step (M=4096) or batched
// over the whole encoder (M=65536, grid (1024,8)) -- identical per-row math.
// (round-11 body, verbatim)
// ---------------------------------------------------------------------------
__global__ __launch_bounds__(256) void proj_mfma(
    const unsigned short* __restrict__ Wh, const unsigned short* __restrict__ Wm,
    const unsigned short* __restrict__ Wl,
    const float* __restrict__ A,
    const float* __restrict__ bias,
    float* __restrict__ C, int ldc)
{
    __shared__ __align__(16) unsigned short wlds[2][3 * 2048]; // 24 KB
    __shared__ __align__(16) float alds[2][64 * 32];           // 16 KB

    const int tid = threadIdx.x;
    const int wv = tid >> 6, lane = tid & 63;
    const int lm = lane & 15, quad = lane >> 4;
    const int nB0 = blockIdx.y * 64;             // output-channel panel base
    const int mB0 = blockIdx.x * 64;             // batch tile base

    // ---- weight staging: 64 rows x 4 x 16B units, 256 threads, 1 issue ----
    const int rw = tid >> 2;                               // row 0..63
    const int sqw = (tid & 3) ^ ((rw >> 1) & 3);           // swizzled src unit
    const size_t wroff = (size_t)(nB0 + rw) * Hdim + (size_t)(sqw * 8);

    // ---- act staging: 2 issues x 32 rows x 8 x 16B units ----
    const int asw = ((lane & 7) ^ (lane >> 3)) * 4;        // swizzled src floats
    const float* asrc[2];
#pragma unroll
    for (int i = 0; i < 2; ++i) {
        const int r = i * 32 + wv * 8 + (lane >> 3);
        asrc[i] = A + (size_t)(mB0 + r) * Hdim + asw;
    }

    // ---- ds_read offsets ----
    int boffW[4];
#pragma unroll
    for (int tn = 0; tn < 4; ++tn) {
        const int r = tn * 16 + lm;
        boffW[tn] = r * 32 + ((quad ^ ((r >> 1) & 3)) * 8);
    }
    const int ra = wv * 16 + lm;                           // wave's act row
    const int boffA1 = ra * 32 + (((2 * quad)     ^ (lm & 7)) << 2);
    const int boffA2 = ra * 32 + (((2 * quad + 1) ^ (lm & 7)) << 2);

    auto stage = [&](int kb, int buf) {
        unsigned short* lb0 = &wlds[buf][wv * 512];
        __builtin_amdgcn_global_load_lds(
            (const __attribute__((address_space(1))) void*)(Wh + wroff + kb),
            (__attribute__((address_space(3))) void*)(lb0), 16, 0, 0);
        __builtin_amdgcn_global_load_lds(
            (const __attribute__((address_space(1))) void*)(Wm + wroff + kb),
            (__attribute__((address_space(3))) void*)(lb0 + 2048), 16, 0, 0);
        __builtin_amdgcn_global_load_lds(
            (const __attribute__((address_space(1))) void*)(Wl + wroff + kb),
            (__attribute__((address_space(3))) void*)(lb0 + 4096), 16, 0, 0);
#pragma unroll
        for (int i = 0; i < 2; ++i) {
            float* lb = &alds[buf][(i * 32 + wv * 8) * 32];
            __builtin_amdgcn_global_load_lds(
                (const __attribute__((address_space(1))) void*)(asrc[i] + kb),
                (__attribute__((address_space(3))) void*)lb, 16, 0, 0);
        }
    };

    f32x4 acc[4];
#pragma unroll
    for (int i = 0; i < 4; ++i) acc[i] = (f32x4){0.f, 0.f, 0.f, 0.f};

    stage(0, 0);
    int cur = 0;

    for (int kc = 0; kc < Hdim; kc += 32) {
        __syncthreads();
        if (kc + 32 < Hdim) stage(kc + 32, cur ^ 1);

        const float* abuf = alds[cur];
        float a8[8];
        *(float4*)&a8[0] = *(const float4*)(abuf + boffA1);
        *(float4*)&a8[4] = *(const float4*)(abuf + boffA2);
        bfrag8 bh, bm, bl;
#pragma unroll
        for (int j = 0; j < 8; ++j) {
            unsigned short h, m, l;
            split3(a8[j], h, m, l);
            bh[j] = (short)h; bm[j] = (short)m; bl[j] = (short)l;
        }

        const unsigned short* bufp = wlds[cur];
#pragma unroll
        for (int tn = 0; tn < 4; ++tn) {
            bfrag8 ah  = *(const bfrag8*)(bufp + boffW[tn]);
            bfrag8 am4 = *(const bfrag8*)(bufp + 2048 + boffW[tn]);
            bfrag8 al  = *(const bfrag8*)(bufp + 4096 + boffW[tn]);
            f32x4 c = acc[tn];
            c = __builtin_amdgcn_mfma_f32_16x16x32_bf16(ah,  bl, c, 0, 0, 0);
            c = __builtin_amdgcn_mfma_f32_16x16x32_bf16(al,  bh, c, 0, 0, 0);
            c = __builtin_amdgcn_mfma_f32_16x16x32_bf16(am4, bm, c, 0, 0, 0);
            c = __builtin_amdgcn_mfma_f32_16x16x32_bf16(ah,  bm, c, 0, 0, 0);
            c = __builtin_amdgcn_mfma_f32_16x16x32_bf16(am4, bh, c, 0, 0, 0);
            c = __builtin_amdgcn_mfma_f32_16x16x32_bf16(ah,  bh, c, 0, 0, 0);
            acc[tn] = c;
        }
        cur ^= 1;
    }

    // epilogue: lane reg r of acc[tn] = channel nB0+tn*16+quad*4+r, batch
    // row mB0+wv*16+lm (planes NOT gate-interleaved).
    const int m = mB0 + wv * 16 + lm;
#pragma unroll
    for (int tn = 0; tn < 4; ++tn) {
        const int n = nB0 + tn * 16 + quad * 4;
        float4 bb = *(const float4*)(bias + n);
        float4 o;
        o.x = acc[tn][0] + bb.x;
        o.y = acc[tn][1] + bb.y;
        o.z = acc[tn][2] + bb.z;
        o.w = acc[tn][3] + bb.w;
        *(float4*)(C + (size_t)m * ldc + n) = o;
    }
}

// ---------------------------------------------------------------------------
// Attention + log-softmax + argmax + state update.
// u2 layout is now [s][b][h] (written row-linear by the batched projection).
// ---------------------------------------------------------------------------
__global__ __launch_bounds__(256) void attn_step(const float* __restrict__ qp,
                                                 const float* __restrict__ u2,
                                                 const float* __restrict__ Vec2,
                                                 float* __restrict__ mask,
                                                 float* __restrict__ ll_ws,
                                                 int* __restrict__ nxt,
                                                 float* __restrict__ out_map,
                                                 float* __restrict__ out_ll,
                                                 int step, int node) {
    const int b = blockIdx.x;
    __shared__ float qpS[Hdim];
    __shared__ float vS[Hdim];
    __shared__ float logitS[Sseq];
    const int tid = threadIdx.x;
    qpS[tid]       = qp[(size_t)b * Hdim + tid];
    qpS[tid + 256] = qp[(size_t)b * Hdim + 256 + tid];
    vS[tid]        = Vec2[tid];
    vS[tid + 256]  = Vec2[256 + tid];
    __syncthreads();

    const int wave = tid >> 6, lane = tid & 63;
    for (int si = 0; si < 4; ++si) {
        int s = wave * 4 + si;
        const float* u2p = u2 + ((size_t)s * Bsz + b) * Hdim;   // [s][b][h]
        float sum = 0.f;
#pragma unroll
        for (int i = 0; i < 8; ++i) {
            int hh = lane + i * 64;
            sum += vS[hh] * tanhf(qpS[hh] + u2p[hh]);
        }
        for (int off = 32; off > 0; off >>= 1) sum += __shfl_down(sum, off);
        if (lane == 0) {
            float pen = step ? mask[b * Sseq + s] * 1e8f : 0.f;
            logitS[s] = 10.f * sum - pen;
        }
    }
    __syncthreads();

    if (tid == 0) {
        float mx = logitS[0];
        int am = 0;
        for (int s = 1; s < Sseq; ++s)
            if (logitS[s] > mx) { mx = logitS[s]; am = s; }
        float se = 0.f;
        for (int s = 0; s < Sseq; ++s) se += expf(logitS[s] - mx);
        float lp = -logf(se);
        float llv = (step ? ll_ws[b] : 0.f) + lp;
        ll_ws[b] = llv;
        out_ll[b] = llv;
        nxt[b] = am;
        if (step == 0) {
            for (int s = 0; s < Sseq; ++s) mask[b * Sseq + s] = (s == am) ? 1.f : 0.f;
        } else {
            mask[b * Sseq + am] += 1.f;
        }
        out_map[b * Sseq + am] = (float)node;
    }
}

// ---------------------------------------------------------------------------
extern "C" void kernel_launch(void* const* d_in, const int* in_sizes, int n_in,
                              void* d_out, int out_size, void* d_ws, size_t ws_size,
                              hipStream_t stream) {
    const float* x       = (const float*)d_in[0];
    const float* emb_W   = (const float*)d_in[1];
    const float* enc_Wih = (const float*)d_in[2];
    const float* enc_Whh = (const float*)d_in[3];
    const float* enc_b   = (const float*)d_in[4];
    const float* dec_Wih = (const float*)d_in[5];
    const float* dec_Whh = (const float*)d_in[6];
    const float* dec_b   = (const float*)d_in[7];
    const float* Wq2     = (const float*)d_in[8];
    const float* bq2     = (const float*)d_in[9];
    const float* Wref2   = (const float*)d_in[10];
    const float* bref2   = (const float*)d_in[11];
    const float* Vec2    = (const float*)d_in[12];
    const float* dec0    = (const float*)d_in[13];

    const size_t BH = (size_t)Bsz * Hdim;

    // workspace layout — base ~195 MB (+134 MB hseq if it fits)
    float* ws      = (float*)d_ws;
    float* u2      = ws;                                   // S*B*H fp32 ([s][b][h])
    float* h0      = u2 + (size_t)Bsz * Sseq * Hdim;       // B*H each
    float* c0      = h0 + BH;
    float* h1      = c0 + BH;
    float* c1      = h1 + BH;
    float* qp      = c1 + BH;
    float* mask    = qp + BH;                              // B*S
    float* ll      = mask + (size_t)Bsz * Sseq;            // B
    int*   nxt     = (int*)(ll + Bsz);                     // B
    float* encBI   = (float*)(nxt + Bsz);                  // 2048 each
    float* decBI   = encBI + H4;
    float* v0bI    = decBI + H4;
    // bf16 weight planes (ushort)
    unsigned short* us = (unsigned short*)(v0bI + H4);
    unsigned short* encEh = us;                       us += (size_t)H4 * Gdim;
    unsigned short* encEm = us;                       us += (size_t)H4 * Gdim;
    unsigned short* encEl = us;                       us += (size_t)H4 * Gdim;
    unsigned short* encWh = us;                       us += (size_t)H4 * Hdim;
    unsigned short* encWm = us;                       us += (size_t)H4 * Hdim;
    unsigned short* encWl = us;                       us += (size_t)H4 * Hdim;
    unsigned short* decEh = us;                       us += (size_t)H4 * Gdim;
    unsigned short* decEm = us;                       us += (size_t)H4 * Gdim;
    unsigned short* decEl = us;                       us += (size_t)H4 * Gdim;
    unsigned short* decWh = us;                       us += (size_t)H4 * Hdim;
    unsigned short* decWm = us;                       us += (size_t)H4 * Hdim;
    unsigned short* decWl = us;                       us += (size_t)H4 * Hdim;
    // projection weight planes (512x512 each)
    unsigned short* prWh = us;                        us += (size_t)Hdim * Hdim;
    unsigned short* prWm = us;                        us += (size_t)Hdim * Hdim;
    unsigned short* prWl = us;                        us += (size_t)Hdim * Hdim;
    unsigned short* pqWh = us;                        us += (size_t)Hdim * Hdim;
    unsigned short* pqWm = us;                        us += (size_t)Hdim * Hdim;
    unsigned short* pqWl = us;                        us += (size_t)Hdim * Hdim;
    // encoder h sequence buffer (16 * B*H fp32) — only if workspace allows
    float* hseq = (float*)us;
    const size_t need = ((char*)(hseq + (size_t)Sseq * BH)) - (char*)d_ws;
    const bool batched = (ws_size >= need);

    float* out_map = (float*)d_out;                        // B*P floats
    float* out_ll  = out_map + (size_t)Bsz * Psteps;       // B floats

    static const int nodes[Psteps] = {0,0,0,0, 1,1,1,1, 2,2,2,2, 3,3,3,3};

    fold_kernel<<<H4, Gdim, 0, stream>>>(enc_Wih, enc_Whh, enc_b,
                                         dec_Wih, dec_Whh, dec_b,
                                         emb_W, dec0,
                                         encEh, encEm, encEl, encWh, encWm, encWl,
                                         decEh, decEm, decEl, decWh, decWm, decWl,
                                         encBI, decBI, v0bI);
    fold_proj<<<dim3(Hdim, 2), 256, 0, stream>>>(Wref2, Wq2,
                                                 prWh, prWm, prWl,
                                                 pqWh, pqWm, pqWl);

    const dim3 gBig(32, 16);    // gates grid: 512 blocks (512 thr), 48KB LDS
    const dim3 gPr(64, 8);      // per-step proj grid:  512 blocks
    const dim3 gPrB(1024, 8);   // batched proj grid: 8192 blocks (M=65536)

    // ---- encoder: 16 fused LSTM steps; u2 projection batched at the end ----
    for (int t = 0; t < Sseq; ++t) {
        float* ho = batched ? (hseq + (size_t)t * BH) : ((t & 1) ? h0 : h1);
        float* co = (t & 1) ? c0 : c1;
        const float* hi = batched ? (hseq + (size_t)(t - 1) * BH)
                                  : ((t & 1) ? h1 : h0);
        const float* ci = (t & 1) ? c1 : c0;
        if (t == 0) {
            gates_mfma<<<gBig, 512, 0, stream>>>(
                encEh, encEm, encEl, Gdim,
                x, Sseq * Gdim, nullptr, 0,
                nullptr, nullptr, nullptr, 0, nullptr,
                encBI, ci, ho, co, 1);
        } else {
            gates_mfma<<<gBig, 512, 0, stream>>>(
                encEh, encEm, encEl, Gdim,
                x + t * Gdim, Sseq * Gdim, nullptr, 0,
                encWh, encWm, encWl, Hdim, hi,
                encBI, ci, ho, co, 0);
        }
        if (!batched) {
            // fallback: per-step u2 projection into [s][b][h] layout
            proj_mfma<<<gPr, 256, 0, stream>>>(prWh, prWm, prWl, ho, bref2,
                                               u2 + (size_t)t * BH, Hdim);
        }
    }
    if (batched) {
        // one M=65536 GEMM: u2[t*B+b] = hseq[t*B+b] @ Wref2^T + bref2
        proj_mfma<<<gPrB, 256, 0, stream>>>(prWh, prWm, prWl, hseq, bref2,
                                            u2, Hdim);
    }

    // ---- decoder: 16 autoregressive steps ----
    for (int p = 0; p < Psteps; ++p) {
        const int u = Sseq + p;
        float* ho = (u & 1) ? h0 : h1;
        float* co = (u & 1) ? c0 : c1;
        const float* hi;
        if (p == 0) hi = batched ? (hseq + (size_t)(Sseq - 1) * BH) : h0;
        else        hi = (u & 1) ? h1 : h0;
        const float* ci = (u & 1) ? c1 : c0;
        if (p == 0) {
            gates_mfma<<<gBig, 512, 0, stream>>>(
                nullptr, nullptr, nullptr, 0,
                nullptr, 0, nullptr, 0,
                decWh, decWm, decWl, Hdim, hi,
                v0bI, ci, ho, co, 0);
        } else {
            gates_mfma<<<gBig, 512, 0, stream>>>(
                decEh, decEm, decEl, Gdim,
                x, Sseq * Gdim, nxt, Gdim,
                decWh, decWm, decWl, Hdim, hi,
                decBI, ci, ho, co, 0);
        }
        proj_mfma<<<gPr, 256, 0, stream>>>(pqWh, pqWm, pqWl, ho, bq2,
                                           qp, Hdim);
        attn_step<<<Bsz, 256, 0, stream>>>(qp, u2, Vec2, mask, ll, nxt,
                                           out_map, out_ll, p, nodes[p]);
    }
}

// Round 17
// 3244.280 us; speedup vs baseline: 1.0042x; 1.0042x over previous
//
#include <hip/hip_runtime.h>
#include <cstddef>

// Problem constants
#define Bsz  4096
#define Sseq 16
#define Gdim 128
#define Edim 256
#define Hdim 512
#define H4   2048
#define Psteps 16
#define BK   16

typedef short bfrag8 __attribute__((ext_vector_type(8)));   // 8 bf16 (4 VGPR)
typedef float f32x4  __attribute__((ext_vector_type(4)));   // MFMA acc

// Exact 3-way bf16 split of fp32 (truncation; residuals exactly representable:
// 24 mantissa bits = 8+8+8). a == hi+mid+lo exactly (normal range).
__device__ __forceinline__ void split3(float f, unsigned short& h,
                                       unsigned short& m, unsigned short& l) {
    unsigned u = __float_as_uint(f);
    h = (unsigned short)(u >> 16);
    float r1 = f - __uint_as_float(u & 0xffff0000u);
    unsigned u1 = __float_as_uint(r1);
    m = (unsigned short)(u1 >> 16);
    float r2 = r1 - __uint_as_float(u1 & 0xffff0000u);
    l = (unsigned short)(__float_as_uint(r2) >> 16);
}

// ---------------------------------------------------------------------------
// Fold kernel: gate-interleaved (row c = j*4+gate) weight prep, emitting
// bf16 hi/mid/lo planes for the MFMA path. Wih rows staged in LDS first
// (coalesced), e-loop reads LDS broadcasts -- same sequential FMA order.
// ---------------------------------------------------------------------------
__global__ void fold_kernel(const float* __restrict__ encWih,
                            const float* __restrict__ encWhh,
                            const float* __restrict__ enc_b,
                            const float* __restrict__ decWih,
                            const float* __restrict__ decWhh,
                            const float* __restrict__ dec_b,
                            const float* __restrict__ embW,
                            const float* __restrict__ dec0,
                            unsigned short* __restrict__ encEh,
                            unsigned short* __restrict__ encEm,
                            unsigned short* __restrict__ encEl,
                            unsigned short* __restrict__ encWh,
                            unsigned short* __restrict__ encWm,
                            unsigned short* __restrict__ encWl,
                            unsigned short* __restrict__ decEh,
                            unsigned short* __restrict__ decEm,
                            unsigned short* __restrict__ decEl,
                            unsigned short* __restrict__ decWh,
                            unsigned short* __restrict__ decWm,
                            unsigned short* __restrict__ decWl,
                            float* __restrict__ encBI, float* __restrict__ decBI,
                            float* __restrict__ v0bI) {
    __shared__ float rE[Edim], rD[Edim];
    const int o = blockIdx.x;            // original row 0..2047 (gate*512 + j)
    const int gate = o >> 9, j = o & 511;
    const int c = j * 4 + gate;          // interleaved row
    const int g = threadIdx.x;           // 0..127
    rE[g]        = encWih[(size_t)o * Edim + g];
    rE[g + Gdim] = encWih[(size_t)o * Edim + g + Gdim];
    rD[g]        = decWih[(size_t)o * Edim + g];
    rD[g + Gdim] = decWih[(size_t)o * Edim + g + Gdim];
    __syncthreads();

    float se = 0.f, sd = 0.f;
#pragma unroll 8
    for (int e = 0; e < Edim; ++e) {
        float w = embW[e * Gdim + g];
        se += rE[e] * w;                 // same sequential order as before
        sd += rD[e] * w;
    }
    unsigned short h, m, l;
    split3(se, h, m, l);
    encEh[(size_t)c * Gdim + g] = h; encEm[(size_t)c * Gdim + g] = m;
    encEl[(size_t)c * Gdim + g] = l;
    split3(sd, h, m, l);
    decEh[(size_t)c * Gdim + g] = h; decEm[(size_t)c * Gdim + g] = m;
    decEl[(size_t)c * Gdim + g] = l;
    for (int k = g; k < Hdim; k += Gdim) {
        split3(encWhh[(size_t)o * Hdim + k], h, m, l);
        encWh[(size_t)c * Hdim + k] = h; encWm[(size_t)c * Hdim + k] = m;
        encWl[(size_t)c * Hdim + k] = l;
        split3(decWhh[(size_t)o * Hdim + k], h, m, l);
        decWh[(size_t)c * Hdim + k] = h; decWm[(size_t)c * Hdim + k] = m;
        decWl[(size_t)c * Hdim + k] = l;
    }
    if (g == 0) {
        encBI[c] = enc_b[o];
        decBI[c] = dec_b[o];
        float s = dec_b[o];
        for (int e = 0; e < Edim; ++e) s += rD[e] * dec0[e];  // same order
        v0bI[c] = s;
    }
}

// ---------------------------------------------------------------------------
// Plane prep for the projection weights (Wref2, Wq2): row-major hi/mid/lo
// bf16 planes, 512x512 each. grid (512, 2).
// ---------------------------------------------------------------------------
__global__ __launch_bounds__(256) void fold_proj(
    const float* __restrict__ Wr, const float* __restrict__ Wq,
    unsigned short* __restrict__ rWh, unsigned short* __restrict__ rWm,
    unsigned short* __restrict__ rWl,
    unsigned short* __restrict__ qWh, unsigned short* __restrict__ qWm,
    unsigned short* __restrict__ qWl) {
    const int o = blockIdx.x;
    const float* src = blockIdx.y ? Wq : Wr;
    unsigned short* ph = blockIdx.y ? qWh : rWh;
    unsigned short* pm = blockIdx.y ? qWm : rWm;
    unsigned short* pl = blockIdx.y ? qWl : rWl;
    for (int k = threadIdx.x; k < Hdim; k += 256) {
        unsigned short h, m, l;
        split3(src[(size_t)o * Hdim + k], h, m, l);
        ph[(size_t)o * Hdim + k] = h;
        pm[(size_t)o * Hdim + k] = m;
        pl[(size_t)o * Hdim + k] = l;
    }
}

// ---------------------------------------------------------------------------
// MFMA gates GEMM + fused LSTM epilogue, fp32-exact via bf16x6 emulation.
// Round-17: round-15 body (best measured: 128m x 128n block, 8 waves, wave
// = 16m x 128n, grid (32,16)=512, weight LDS double-buffer 48 KB, direct
// act loads) + COALESCED EPILOGUE: the old epilogue issued 64 scattered 4B
// stores per lane (WRITE_SIZE 67 MB vs 16 MB ideal, 4x partial-line write
// amplification) and the same scatter for the c_in read. Now the dead
// weight-LDS is reused as a [128][33]-padded f32 bounce buffer:
//   phase 0: coalesced float4 c_in tile load -> LDS
//   phase 1: per-lane gate math (identical FP ops; co from LDS, cn/hv
//            scattered to LDS -- +1-pad => ~2-way conflicts, free)
//   phase 2: coalesced 32B/lane float4 stores of full 128B row segments.
// fp32 LDS roundtrip is exact -> output bit-identical.
// ---------------------------------------------------------------------------
__global__ __launch_bounds__(512) void gates_mfma(
    const unsigned short* __restrict__ Wh1, const unsigned short* __restrict__ Wm1,
    const unsigned short* __restrict__ Wl1, int K1,
    const float* __restrict__ X, int ldx,
    const int* __restrict__ gather, int gmul,
    const unsigned short* __restrict__ Wh2, const unsigned short* __restrict__ Wm2,
    const unsigned short* __restrict__ Wl2, int K2,
    const float* __restrict__ Hin,
    const float* __restrict__ biasI,
    const float* __restrict__ c_in, float* __restrict__ h_out,
    float* __restrict__ c_out, int czero)
{
    __shared__ __align__(16) unsigned short wlds[2][3 * 4096]; // 48 KB

    const int tid = threadIdx.x;                 // 0..511
    const int wv = tid >> 6, lane = tid & 63;    // 8 waves
    const int lm = lane & 15, quad = lane >> 4;
    const int c0 = blockIdx.y * 128;             // block n-panel base row
    const int mB0 = blockIdx.x * 128;            // block batch base (128 rows)

    const int mrow = mB0 + wv * 16 + lm;         // this lane's act/output row

    // ---- weight staging: 128 rows x 4 units x 3 planes; 512 thr, 1 unit
    //      per thread per plane. Wave wv stages rows wv*16..wv*16+15.
    const int srow = wv * 16 + (lane >> 2);
    const int sqs = (lane & 3) ^ ((srow >> 1) & 3);   // pre-swizzled src unit
    const size_t roff1 = (size_t)(c0 + srow) * K1 + (size_t)(sqs * 8);
    const size_t roff2 = (size_t)(c0 + srow) * K2 + (size_t)(sqs * 8);

    // ---- act pointers (direct global; wave rows are private, no dup) ----
    const float* xr = nullptr;
    const float* hr = nullptr;
    if (X) {
        size_t off = (size_t)mrow * ldx;
        if (gather) off += (size_t)gather[mrow] * gmul;
        xr = X + off;
    }
    if (Hin) hr = Hin + (size_t)mrow * K2;

    // ---- weight ds_read fragment offsets (ushort units), 8 n-tiles ----
    int boffW[8];
#pragma unroll
    for (int tn = 0; tn < 8; ++tn) {
        const int r = tn * 16 + lm;
        boffW[tn] = r * 32 + ((quad ^ ((r >> 1) & 3)) * 8);
    }

    auto stage = [&](int kcN, int buf) {
        const bool nX = kcN < K1;
        const int kb = nX ? kcN : kcN - K1;
        unsigned short* lb = &wlds[buf][wv * 512];
        const unsigned short* gh = (nX ? Wh1 + roff1 : Wh2 + roff2) + kb;
        const unsigned short* gm = (nX ? Wm1 + roff1 : Wm2 + roff2) + kb;
        const unsigned short* gl = (nX ? Wl1 + roff1 : Wl2 + roff2) + kb;
        __builtin_amdgcn_global_load_lds(
            (const __attribute__((address_space(1))) void*)gh,
            (__attribute__((address_space(3))) void*)(lb), 16, 0, 0);
        __builtin_amdgcn_global_load_lds(
            (const __attribute__((address_space(1))) void*)gm,
            (__attribute__((address_space(3))) void*)(lb + 4096), 16, 0, 0);
        __builtin_amdgcn_global_load_lds(
            (const __attribute__((address_space(1))) void*)gl,
            (__attribute__((address_space(3))) void*)(lb + 8192), 16, 0, 0);
    };

    f32x4 acc[8];
#pragma unroll
    for (int i = 0; i < 8; ++i) acc[i] = (f32x4){0.f, 0.f, 0.f, 0.f};

    const int KT = K1 + K2;
    stage(0, 0);
    int cur = 0;

    for (int kc = 0; kc < KT; kc += 32) {
        __syncthreads();                       // drains staged loads for buf[cur]
        if (kc + 32 < KT) stage(kc + 32, cur ^ 1);

        const bool inX = kc < K1;
        const int kk = (inX ? kc : kc - K1) + quad * 8;

        // this wave's single act fragment: direct global, split3 in VALU
        const float* p = (inX ? xr : hr) + kk;
        float a8[8];
        *(float4*)&a8[0] = *(const float4*)(p);
        *(float4*)&a8[4] = *(const float4*)(p + 4);
        bfrag8 bh, bm, bl;
#pragma unroll
        for (int j = 0; j < 8; ++j) {
            unsigned short h, m, l;
            split3(a8[j], h, m, l);
            bh[j] = (short)h; bm[j] = (short)m; bl[j] = (short)l;
        }

        const unsigned short* bufp = wlds[cur];
#pragma unroll
        for (int hh = 0; hh < 2; ++hh) {
            bfrag8 ah[4], am4[4], al[4];
#pragma unroll
            for (int t = 0; t < 4; ++t) {
                const int tn = hh * 4 + t;
                ah[t]  = *(const bfrag8*)(bufp + boffW[tn]);
                am4[t] = *(const bfrag8*)(bufp + 4096 + boffW[tn]);
                al[t]  = *(const bfrag8*)(bufp + 8192 + boffW[tn]);
            }
#pragma unroll
            for (int t = 0; t < 4; ++t) {
                const int tn = hh * 4 + t;
                f32x4 c = acc[tn];
                c = __builtin_amdgcn_mfma_f32_16x16x32_bf16(ah[t], bl, c, 0, 0, 0);
                c = __builtin_amdgcn_mfma_f32_16x16x32_bf16(al[t], bh, c, 0, 0, 0);
                c = __builtin_amdgcn_mfma_f32_16x16x32_bf16(am4[t], bm, c, 0, 0, 0);
                c = __builtin_amdgcn_mfma_f32_16x16x32_bf16(ah[t], bm, c, 0, 0, 0);
                c = __builtin_amdgcn_mfma_f32_16x16x32_bf16(am4[t], bh, c, 0, 0, 0);
                c = __builtin_amdgcn_mfma_f32_16x16x32_bf16(ah[t], bh, c, 0, 0, 0);
                acc[tn] = c;
            }
        }
        cur ^= 1;
    }

    // ---- coalesced epilogue: wlds reused as [128][33] f32 bounce buffers --
    __syncthreads();                 // all waves done reading wlds
    float* hs = (float*)&wlds[0][0];             // [128][33]
    float* cs = hs + 128 * 33;                   // [128][33] (33.8 KB total)

    const int er = tid >> 2;                     // bounce row 0..127
    const int ec = (tid & 3) * 8;                // bounce col 0,8,16,24
    const size_t gbase = (size_t)(mB0 + er) * Hdim + (c0 >> 2) + ec;

    // phase 0: coalesced c_in tile load -> cs
    if (!czero) {
        float4 ci0 = *(const float4*)(c_in + gbase);
        float4 ci1 = *(const float4*)(c_in + gbase + 4);
        float* dst = cs + er * 33 + ec;
        dst[0] = ci0.x; dst[1] = ci0.y; dst[2] = ci0.z; dst[3] = ci0.w;
        dst[4] = ci1.x; dst[5] = ci1.y; dst[6] = ci1.z; dst[7] = ci1.w;
    }
    __syncthreads();

    // phase 1: gate math (identical FP ops), scatter to LDS
    const int lr = wv * 16 + lm;                 // this lane's local row
#pragma unroll
    for (int tn = 0; tn < 8; ++tn) {
        const int nb = c0 + tn * 16 + quad * 4;
        float4 bb = *(const float4*)(biasI + nb);
        const int jl = tn * 4 + quad;            // local col 0..31
        float gi = acc[tn][0] + bb.x;
        float gf = acc[tn][1] + bb.y;
        float gg = acc[tn][2] + bb.z;
        float go = acc[tn][3] + bb.w;
        float si = 1.f / (1.f + expf(-gi));
        float sf = 1.f / (1.f + expf(-gf));
        float so = 1.f / (1.f + expf(-go));
        float co = czero ? 0.f : cs[lr * 33 + jl];
        float cn = si * tanhf(gg) + sf * co;
        cs[lr * 33 + jl] = cn;
        hs[lr * 33 + jl] = so * tanhf(cn);
    }
    __syncthreads();

    // phase 2: coalesced float4 stores (32B/thread, full 128B row segments)
    {
        const float* hsrc = hs + er * 33 + ec;
        const float* csrc = cs + er * 33 + ec;
        float4 h0v, h1v, c0v, c1v;
        h0v.x = hsrc[0]; h0v.y = hsrc[1]; h0v.z = hsrc[2]; h0v.w = hsrc[3];
        h1v.x = hsrc[4]; h1v.y = hsrc[5]; h1v.z = hsrc[6]; h1v.w = hsrc[7];
        c0v.x = csrc[0]; c0v.y = csrc[1]; c0v.z = csrc[2]; c0v.w = csrc[3];
        c1v.x = csrc[4]; c1v.y = csrc[5]; c1v.z = csrc[6]; c1v.w = csrc[7];
        *(float4*)(h_out + gbase)     = h0v;
        *(float4*)(h_out + gbase + 4) = h1v;
        *(float4*)(c_out + gbase)     = c0v;
        *(float4*)(c_out + gbase + 4) = c1v;
    }
}

// ---------------------------------------------------------------------------
// MFMA projection GEMM: C[m] = A[m] @ W^T + bias (W via bf16x6 planes,
// K=512). 64m x 64n block, 4 waves (wave = 16m x 64n, acc 4x1), grid
// (64,8)=512, dual LDS double-buffer staging with both-sides swizzles.
// (round-11 body, verbatim)
// ---------------------------------------------------------------------------
__global__ __launch_bounds__(256) void proj_mfma(
    const unsigned short* __restrict__ Wh, const unsigned short* __restrict__ Wm,
    const unsigned short* __restrict__ Wl,
    const float* __restrict__ A,
    const float* __restrict__ bias,
    float* __restrict__ C, int ldc)
{
    __shared__ __align__(16) unsigned short wlds[2][3 * 2048]; // 24 KB
    __shared__ __align__(16) float alds[2][64 * 32];           // 16 KB

    const int tid = threadIdx.x;
    const int wv = tid >> 6, lane = tid & 63;
    const int lm = lane & 15, quad = lane >> 4;
    const int nB0 = blockIdx.y * 64;             // output-channel panel base
    const int mB0 = blockIdx.x * 64;             // batch tile base

    // ---- weight staging: 64 rows x 4 x 16B units, 256 threads, 1 issue ----
    const int rw = tid >> 2;                               // row 0..63
    const int sqw = (tid & 3) ^ ((rw >> 1) & 3);           // swizzled src unit
    const size_t wroff = (size_t)(nB0 + rw) * Hdim + (size_t)(sqw * 8);

    // ---- act staging: 2 issues x 32 rows x 8 x 16B units ----
    const int asw = ((lane & 7) ^ (lane >> 3)) * 4;        // swizzled src floats
    const float* asrc[2];
#pragma unroll
    for (int i = 0; i < 2; ++i) {
        const int r = i * 32 + wv * 8 + (lane >> 3);
        asrc[i] = A + (size_t)(mB0 + r) * Hdim + asw;
    }

    // ---- ds_read offsets ----
    int boffW[4];
#pragma unroll
    for (int tn = 0; tn < 4; ++tn) {
        const int r = tn * 16 + lm;
        boffW[tn] = r * 32 + ((quad ^ ((r >> 1) & 3)) * 8);
    }
    const int ra = wv * 16 + lm;                           // wave's act row
    const int boffA1 = ra * 32 + (((2 * quad)     ^ (lm & 7)) << 2);
    const int boffA2 = ra * 32 + (((2 * quad + 1) ^ (lm & 7)) << 2);

    auto stage = [&](int kb, int buf) {
        unsigned short* lb0 = &wlds[buf][wv * 512];
        __builtin_amdgcn_global_load_lds(
            (const __attribute__((address_space(1))) void*)(Wh + wroff + kb),
            (__attribute__((address_space(3))) void*)(lb0), 16, 0, 0);
        __builtin_amdgcn_global_load_lds(
            (const __attribute__((address_space(1))) void*)(Wm + wroff + kb),
            (__attribute__((address_space(3))) void*)(lb0 + 2048), 16, 0, 0);
        __builtin_amdgcn_global_load_lds(
            (const __attribute__((address_space(1))) void*)(Wl + wroff + kb),
            (__attribute__((address_space(3))) void*)(lb0 + 4096), 16, 0, 0);
#pragma unroll
        for (int i = 0; i < 2; ++i) {
            float* lb = &alds[buf][(i * 32 + wv * 8) * 32];
            __builtin_amdgcn_global_load_lds(
                (const __attribute__((address_space(1))) void*)(asrc[i] + kb),
                (__attribute__((address_space(3))) void*)lb, 16, 0, 0);
        }
    };

    f32x4 acc[4];
#pragma unroll
    for (int i = 0; i < 4; ++i) acc[i] = (f32x4){0.f, 0.f, 0.f, 0.f};

    stage(0, 0);
    int cur = 0;

    for (int kc = 0; kc < Hdim; kc += 32) {
        __syncthreads();
        if (kc + 32 < Hdim) stage(kc + 32, cur ^ 1);

        const float* abuf = alds[cur];
        float a8[8];
        *(float4*)&a8[0] = *(const float4*)(abuf + boffA1);
        *(float4*)&a8[4] = *(const float4*)(abuf + boffA2);
        bfrag8 bh, bm, bl;
#pragma unroll
        for (int j = 0; j < 8; ++j) {
            unsigned short h, m, l;
            split3(a8[j], h, m, l);
            bh[j] = (short)h; bm[j] = (short)m; bl[j] = (short)l;
        }

        const unsigned short* bufp = wlds[cur];
#pragma unroll
        for (int tn = 0; tn < 4; ++tn) {
            bfrag8 ah  = *(const bfrag8*)(bufp + boffW[tn]);
            bfrag8 am4 = *(const bfrag8*)(bufp + 2048 + boffW[tn]);
            bfrag8 al  = *(const bfrag8*)(bufp + 4096 + boffW[tn]);
            f32x4 c = acc[tn];
            c = __builtin_amdgcn_mfma_f32_16x16x32_bf16(ah,  bl, c, 0, 0, 0);
            c = __builtin_amdgcn_mfma_f32_16x16x32_bf16(al,  bh, c, 0, 0, 0);
            c = __builtin_amdgcn_mfma_f32_16x16x32_bf16(am4, bm, c, 0, 0, 0);
            c = __builtin_amdgcn_mfma_f32_16x16x32_bf16(ah,  bm, c, 0, 0, 0);
            c = __builtin_amdgcn_mfma_f32_16x16x32_bf16(am4, bh, c, 0, 0, 0);
            c = __builtin_amdgcn_mfma_f32_16x16x32_bf16(ah,  bh, c, 0, 0, 0);
            acc[tn] = c;
        }
        cur ^= 1;
    }

    // epilogue: lane reg r of acc[tn] = channel nB0+tn*16+quad*4+r, batch
    // row mB0+wv*16+lm (planes NOT gate-interleaved).
    const int m = mB0 + wv * 16 + lm;
#pragma unroll
    for (int tn = 0; tn < 4; ++tn) {
        const int n = nB0 + tn * 16 + quad * 4;
        float4 bb = *(const float4*)(bias + n);
        float4 o;
        o.x = acc[tn][0] + bb.x;
        o.y = acc[tn][1] + bb.y;
        o.z = acc[tn][2] + bb.z;
        o.w = acc[tn][3] + bb.w;
        *(float4*)(C + (size_t)m * ldc + n) = o;
    }
}

// ---------------------------------------------------------------------------
// Attention + log-softmax + argmax + state update. u2 layout [s][b][h].
// ---------------------------------------------------------------------------
__global__ __launch_bounds__(256) void attn_step(const float* __restrict__ qp,
                                                 const float* __restrict__ u2,
                                                 const float* __restrict__ Vec2,
                                                 float* __restrict__ mask,
                                                 float* __restrict__ ll_ws,
                                                 int* __restrict__ nxt,
                                                 float* __restrict__ out_map,
                                                 float* __restrict__ out_ll,
                                                 int step, int node) {
    const int b = blockIdx.x;
    __shared__ float qpS[Hdim];
    __shared__ float vS[Hdim];
    __shared__ float logitS[Sseq];
    const int tid = threadIdx.x;
    qpS[tid]       = qp[(size_t)b * Hdim + tid];
    qpS[tid + 256] = qp[(size_t)b * Hdim + 256 + tid];
    vS[tid]        = Vec2[tid];
    vS[tid + 256]  = Vec2[256 + tid];
    __syncthreads();

    const int wave = tid >> 6, lane = tid & 63;
    for (int si = 0; si < 4; ++si) {
        int s = wave * 4 + si;
        const float* u2p = u2 + ((size_t)s * Bsz + b) * Hdim;   // [s][b][h]
        float sum = 0.f;
#pragma unroll
        for (int i = 0; i < 8; ++i) {
            int hh = lane + i * 64;
            sum += vS[hh] * tanhf(qpS[hh] + u2p[hh]);
        }
        for (int off = 32; off > 0; off >>= 1) sum += __shfl_down(sum, off);
        if (lane == 0) {
            float pen = step ? mask[b * Sseq + s] * 1e8f : 0.f;
            logitS[s] = 10.f * sum - pen;
        }
    }
    __syncthreads();

    if (tid == 0) {
        float mx = logitS[0];
        int am = 0;
        for (int s = 1; s < Sseq; ++s)
            if (logitS[s] > mx) { mx = logitS[s]; am = s; }
        float se = 0.f;
        for (int s = 0; s < Sseq; ++s) se += expf(logitS[s] - mx);
        float lp = -logf(se);
        float llv = (step ? ll_ws[b] : 0.f) + lp;
        ll_ws[b] = llv;
        out_ll[b] = llv;
        nxt[b] = am;
        if (step == 0) {
            for (int s = 0; s < Sseq; ++s) mask[b * Sseq + s] = (s == am) ? 1.f : 0.f;
        } else {
            mask[b * Sseq + am] += 1.f;
        }
        out_map[b * Sseq + am] = (float)node;
    }
}

// ---------------------------------------------------------------------------
extern "C" void kernel_launch(void* const* d_in, const int* in_sizes, int n_in,
                              void* d_out, int out_size, void* d_ws, size_t ws_size,
                              hipStream_t stream) {
    const float* x       = (const float*)d_in[0];
    const float* emb_W   = (const float*)d_in[1];
    const float* enc_Wih = (const float*)d_in[2];
    const float* enc_Whh = (const float*)d_in[3];
    const float* enc_b   = (const float*)d_in[4];
    const float* dec_Wih = (const float*)d_in[5];
    const float* dec_Whh = (const float*)d_in[6];
    const float* dec_b   = (const float*)d_in[7];
    const float* Wq2     = (const float*)d_in[8];
    const float* bq2     = (const float*)d_in[9];
    const float* Wref2   = (const float*)d_in[10];
    const float* bref2   = (const float*)d_in[11];
    const float* Vec2    = (const float*)d_in[12];
    const float* dec0    = (const float*)d_in[13];

    const size_t BH = (size_t)Bsz * Hdim;

    // workspace layout — ~195 MB
    float* ws      = (float*)d_ws;
    float* u2      = ws;                                   // S*B*H fp32 ([s][b][h])
    float* h0      = u2 + (size_t)Bsz * Sseq * Hdim;       // B*H each
    float* c0      = h0 + BH;
    float* h1      = c0 + BH;
    float* c1      = h1 + BH;
    float* qp      = c1 + BH;
    float* mask    = qp + BH;                              // B*S
    float* ll      = mask + (size_t)Bsz * Sseq;            // B
    int*   nxt     = (int*)(ll + Bsz);                     // B
    float* encBI   = (float*)(nxt + Bsz);                  // 2048 each
    float* decBI   = encBI + H4;
    float* v0bI    = decBI + H4;
    // bf16 weight planes (ushort)
    unsigned short* us = (unsigned short*)(v0bI + H4);
    unsigned short* encEh = us;                       us += (size_t)H4 * Gdim;
    unsigned short* encEm = us;                       us += (size_t)H4 * Gdim;
    unsigned short* encEl = us;                       us += (size_t)H4 * Gdim;
    unsigned short* encWh = us;                       us += (size_t)H4 * Hdim;
    unsigned short* encWm = us;                       us += (size_t)H4 * Hdim;
    unsigned short* encWl = us;                       us += (size_t)H4 * Hdim;
    unsigned short* decEh = us;                       us += (size_t)H4 * Gdim;
    unsigned short* decEm = us;                       us += (size_t)H4 * Gdim;
    unsigned short* decEl = us;                       us += (size_t)H4 * Gdim;
    unsigned short* decWh = us;                       us += (size_t)H4 * Hdim;
    unsigned short* decWm = us;                       us += (size_t)H4 * Hdim;
    unsigned short* decWl = us;                       us += (size_t)H4 * Hdim;
    // projection weight planes (512x512 each)
    unsigned short* prWh = us;                        us += (size_t)Hdim * Hdim;
    unsigned short* prWm = us;                        us += (size_t)Hdim * Hdim;
    unsigned short* prWl = us;                        us += (size_t)Hdim * Hdim;
    unsigned short* pqWh = us;                        us += (size_t)Hdim * Hdim;
    unsigned short* pqWm = us;                        us += (size_t)Hdim * Hdim;
    unsigned short* pqWl = us;                        us += (size_t)Hdim * Hdim;

    float* out_map = (float*)d_out;                        // B*P floats
    float* out_ll  = out_map + (size_t)Bsz * Psteps;       // B floats

    static const int nodes[Psteps] = {0,0,0,0, 1,1,1,1, 2,2,2,2, 3,3,3,3};

    fold_kernel<<<H4, Gdim, 0, stream>>>(enc_Wih, enc_Whh, enc_b,
                                         dec_Wih, dec_Whh, dec_b,
                                         emb_W, dec0,
                                         encEh, encEm, encEl, encWh, encWm, encWl,
                                         decEh, decEm, decEl, decWh, decWm, decWl,
                                         encBI, decBI, v0bI);
    fold_proj<<<dim3(Hdim, 2), 256, 0, stream>>>(Wref2, Wq2,
                                                 prWh, prWm, prWl,
                                                 pqWh, pqWm, pqWl);

    const dim3 gBig(32, 16);    // gates grid: 512 blocks (512 thr), 48KB LDS
    const dim3 gPr(64, 8);      // proj grid:  512 blocks = 2/CU

    // ---- encoder: 16 fused LSTM steps + u2[t] projection of h(t) ----
    for (int t = 0; t < Sseq; ++t) {
        float* ho = (t & 1) ? h0 : h1;
        float* co = (t & 1) ? c0 : c1;
        const float* hi = (t & 1) ? h1 : h0;
        const float* ci = (t & 1) ? c1 : c0;
        if (t == 0) {
            gates_mfma<<<gBig, 512, 0, stream>>>(
                encEh, encEm, encEl, Gdim,
                x, Sseq * Gdim, nullptr, 0,
                nullptr, nullptr, nullptr, 0, nullptr,
                encBI, ci, ho, co, 1);
        } else {
            gates_mfma<<<gBig, 512, 0, stream>>>(
                encEh, encEm, encEl, Gdim,
                x + t * Gdim, Sseq * Gdim, nullptr, 0,
                encWh, encWm, encWl, Hdim, hi,
                encBI, ci, ho, co, 0);
        }
        // u2[t] projection into [s][b][h] layout
        proj_mfma<<<gPr, 256, 0, stream>>>(prWh, prWm, prWl, ho, bref2,
                                           u2 + (size_t)t * BH, Hdim);
    }

    // ---- decoder: 16 autoregressive steps ----
    for (int p = 0; p < Psteps; ++p) {
        const int u = Sseq + p;
        float* ho = (u & 1) ? h0 : h1;
        float* co = (u & 1) ? c0 : c1;
        const float* hi = (u & 1) ? h1 : h0;
        const float* ci = (u & 1) ? c1 : c0;
        if (p == 0) {
            gates_mfma<<<gBig, 512, 0, stream>>>(
                nullptr, nullptr, nullptr, 0,
                nullptr, 0, nullptr, 0,
                decWh, decWm, decWl, Hdim, hi,
                v0bI, ci, ho, co, 0);
        } else {
            gates_mfma<<<gBig, 512, 0, stream>>>(
                decEh, decEm, decEl, Gdim,
                x, Sseq * Gdim, nxt, Gdim,
                decWh, decWm, decWl, Hdim, hi,
                decBI, ci, ho, co, 0);
        }
        proj_mfma<<<gPr, 256, 0, stream>>>(pqWh, pqWm, pqWl, ho, bq2,
                                           qp, Hdim);
        attn_step<<<Bsz, 256, 0, stream>>>(qp, u2, Vec2, mask, ll, nxt,
                                           out_map, out_ll, p, nodes[p]);
    }
}

// Round 18
// 3170.032 us; speedup vs baseline: 1.0277x; 1.0234x over previous
//
#include <hip/hip_runtime.h>
#include <cstddef>

// Problem constants
#define Bsz  4096
#define Sseq 16
#define Gdim 128
#define Edim 256
#define Hdim 512
#define H4   2048
#define Psteps 16
#define BK   16

typedef short bfrag8 __attribute__((ext_vector_type(8)));   // 8 bf16 (4 VGPR)
typedef float f32x4  __attribute__((ext_vector_type(4)));   // MFMA acc

// Exact 3-way bf16 split of fp32 (truncation; residuals exactly representable:
// 24 mantissa bits = 8+8+8). a == hi+mid+lo exactly (normal range).
__device__ __forceinline__ void split3(float f, unsigned short& h,
                                       unsigned short& m, unsigned short& l) {
    unsigned u = __float_as_uint(f);
    h = (unsigned short)(u >> 16);
    float r1 = f - __uint_as_float(u & 0xffff0000u);
    unsigned u1 = __float_as_uint(r1);
    m = (unsigned short)(u1 >> 16);
    float r2 = r1 - __uint_as_float(u1 & 0xffff0000u);
    l = (unsigned short)(__float_as_uint(r2) >> 16);
}

// ---------------------------------------------------------------------------
// Fold kernel: gate-interleaved (row c = j*4+gate) weight prep, emitting
// bf16 hi/mid/lo planes for the MFMA path. Wih rows staged in LDS first
// (coalesced), e-loop reads LDS broadcasts -- same sequential FMA order.
// ---------------------------------------------------------------------------
__global__ void fold_kernel(const float* __restrict__ encWih,
                            const float* __restrict__ encWhh,
                            const float* __restrict__ enc_b,
                            const float* __restrict__ decWih,
                            const float* __restrict__ decWhh,
                            const float* __restrict__ dec_b,
                            const float* __restrict__ embW,
                            const float* __restrict__ dec0,
                            unsigned short* __restrict__ encEh,
                            unsigned short* __restrict__ encEm,
                            unsigned short* __restrict__ encEl,
                            unsigned short* __restrict__ encWh,
                            unsigned short* __restrict__ encWm,
                            unsigned short* __restrict__ encWl,
                            unsigned short* __restrict__ decEh,
                            unsigned short* __restrict__ decEm,
                            unsigned short* __restrict__ decEl,
                            unsigned short* __restrict__ decWh,
                            unsigned short* __restrict__ decWm,
                            unsigned short* __restrict__ decWl,
                            float* __restrict__ encBI, float* __restrict__ decBI,
                            float* __restrict__ v0bI) {
    __shared__ float rE[Edim], rD[Edim];
    const int o = blockIdx.x;            // original row 0..2047 (gate*512 + j)
    const int gate = o >> 9, j = o & 511;
    const int c = j * 4 + gate;          // interleaved row
    const int g = threadIdx.x;           // 0..127
    rE[g]        = encWih[(size_t)o * Edim + g];
    rE[g + Gdim] = encWih[(size_t)o * Edim + g + Gdim];
    rD[g]        = decWih[(size_t)o * Edim + g];
    rD[g + Gdim] = decWih[(size_t)o * Edim + g + Gdim];
    __syncthreads();

    float se = 0.f, sd = 0.f;
#pragma unroll 8
    for (int e = 0; e < Edim; ++e) {
        float w = embW[e * Gdim + g];
        se += rE[e] * w;                 // same sequential order as before
        sd += rD[e] * w;
    }
    unsigned short h, m, l;
    split3(se, h, m, l);
    encEh[(size_t)c * Gdim + g] = h; encEm[(size_t)c * Gdim + g] = m;
    encEl[(size_t)c * Gdim + g] = l;
    split3(sd, h, m, l);
    decEh[(size_t)c * Gdim + g] = h; decEm[(size_t)c * Gdim + g] = m;
    decEl[(size_t)c * Gdim + g] = l;
    for (int k = g; k < Hdim; k += Gdim) {
        split3(encWhh[(size_t)o * Hdim + k], h, m, l);
        encWh[(size_t)c * Hdim + k] = h; encWm[(size_t)c * Hdim + k] = m;
        encWl[(size_t)c * Hdim + k] = l;
        split3(decWhh[(size_t)o * Hdim + k], h, m, l);
        decWh[(size_t)c * Hdim + k] = h; decWm[(size_t)c * Hdim + k] = m;
        decWl[(size_t)c * Hdim + k] = l;
    }
    if (g == 0) {
        encBI[c] = enc_b[o];
        decBI[c] = dec_b[o];
        float s = dec_b[o];
        for (int e = 0; e < Edim; ++e) s += rD[e] * dec0[e];  // same order
        v0bI[c] = s;
    }
}

// ---------------------------------------------------------------------------
// Plane prep for the projection weights (Wref2, Wq2): row-major hi/mid/lo
// bf16 planes, 512x512 each. grid (512, 2).
// ---------------------------------------------------------------------------
__global__ __launch_bounds__(256) void fold_proj(
    const float* __restrict__ Wr, const float* __restrict__ Wq,
    unsigned short* __restrict__ rWh, unsigned short* __restrict__ rWm,
    unsigned short* __restrict__ rWl,
    unsigned short* __restrict__ qWh, unsigned short* __restrict__ qWm,
    unsigned short* __restrict__ qWl) {
    const int o = blockIdx.x;
    const float* src = blockIdx.y ? Wq : Wr;
    unsigned short* ph = blockIdx.y ? qWh : rWh;
    unsigned short* pm = blockIdx.y ? qWm : rWm;
    unsigned short* pl = blockIdx.y ? qWl : rWl;
    for (int k = threadIdx.x; k < Hdim; k += 256) {
        unsigned short h, m, l;
        split3(src[(size_t)o * Hdim + k], h, m, l);
        ph[(size_t)o * Hdim + k] = h;
        pm[(size_t)o * Hdim + k] = m;
        pl[(size_t)o * Hdim + k] = l;
    }
}

// ---------------------------------------------------------------------------
// MFMA gates GEMM + fused LSTM epilogue, fp32-exact via bf16x6 emulation.
// Round-18: round-17 body with ONE change in the K-loop issue order.
// vmcnt is a FIFO retiring in order, so with [stage(next); act loads] the
// compiler's wait before split3 must be vmcnt(0) -- draining the NEXT
// chunk's weight staging mid-compute, every chunk. Now the act loads are
// issued FIRST (pinned by one sched_barrier(0)), so their wait is vmcnt(3)
// and the 3 stage loads stay in flight until the next __syncthreads -- a
// full chunk of latency hiding. Same loads, same barriers, same MFMA order
// -> bit-identical output.
// ---------------------------------------------------------------------------
__global__ __launch_bounds__(512) void gates_mfma(
    const unsigned short* __restrict__ Wh1, const unsigned short* __restrict__ Wm1,
    const unsigned short* __restrict__ Wl1, int K1,
    const float* __restrict__ X, int ldx,
    const int* __restrict__ gather, int gmul,
    const unsigned short* __restrict__ Wh2, const unsigned short* __restrict__ Wm2,
    const unsigned short* __restrict__ Wl2, int K2,
    const float* __restrict__ Hin,
    const float* __restrict__ biasI,
    const float* __restrict__ c_in, float* __restrict__ h_out,
    float* __restrict__ c_out, int czero)
{
    __shared__ __align__(16) unsigned short wlds[2][3 * 4096]; // 48 KB

    const int tid = threadIdx.x;                 // 0..511
    const int wv = tid >> 6, lane = tid & 63;    // 8 waves
    const int lm = lane & 15, quad = lane >> 4;
    const int c0 = blockIdx.y * 128;             // block n-panel base row
    const int mB0 = blockIdx.x * 128;            // block batch base (128 rows)

    const int mrow = mB0 + wv * 16 + lm;         // this lane's act/output row

    // ---- weight staging: 128 rows x 4 units x 3 planes; 512 thr, 1 unit
    //      per thread per plane. Wave wv stages rows wv*16..wv*16+15.
    const int srow = wv * 16 + (lane >> 2);
    const int sqs = (lane & 3) ^ ((srow >> 1) & 3);   // pre-swizzled src unit
    const size_t roff1 = (size_t)(c0 + srow) * K1 + (size_t)(sqs * 8);
    const size_t roff2 = (size_t)(c0 + srow) * K2 + (size_t)(sqs * 8);

    // ---- act pointers (direct global; wave rows are private, no dup) ----
    const float* xr = nullptr;
    const float* hr = nullptr;
    if (X) {
        size_t off = (size_t)mrow * ldx;
        if (gather) off += (size_t)gather[mrow] * gmul;
        xr = X + off;
    }
    if (Hin) hr = Hin + (size_t)mrow * K2;

    // ---- weight ds_read fragment offsets (ushort units), 8 n-tiles ----
    int boffW[8];
#pragma unroll
    for (int tn = 0; tn < 8; ++tn) {
        const int r = tn * 16 + lm;
        boffW[tn] = r * 32 + ((quad ^ ((r >> 1) & 3)) * 8);
    }

    auto stage = [&](int kcN, int buf) {
        const bool nX = kcN < K1;
        const int kb = nX ? kcN : kcN - K1;
        unsigned short* lb = &wlds[buf][wv * 512];
        const unsigned short* gh = (nX ? Wh1 + roff1 : Wh2 + roff2) + kb;
        const unsigned short* gm = (nX ? Wm1 + roff1 : Wm2 + roff2) + kb;
        const unsigned short* gl = (nX ? Wl1 + roff1 : Wl2 + roff2) + kb;
        __builtin_amdgcn_global_load_lds(
            (const __attribute__((address_space(1))) void*)gh,
            (__attribute__((address_space(3))) void*)(lb), 16, 0, 0);
        __builtin_amdgcn_global_load_lds(
            (const __attribute__((address_space(1))) void*)gm,
            (__attribute__((address_space(3))) void*)(lb + 4096), 16, 0, 0);
        __builtin_amdgcn_global_load_lds(
            (const __attribute__((address_space(1))) void*)gl,
            (__attribute__((address_space(3))) void*)(lb + 8192), 16, 0, 0);
    };

    f32x4 acc[8];
#pragma unroll
    for (int i = 0; i < 8; ++i) acc[i] = (f32x4){0.f, 0.f, 0.f, 0.f};

    const int KT = K1 + K2;
    stage(0, 0);
    int cur = 0;

    for (int kc = 0; kc < KT; kc += 32) {
        __syncthreads();                       // drains staged loads for buf[cur]

        const bool inX = kc < K1;
        const int kk = (inX ? kc : kc - K1) + quad * 8;

        // 1) act loads FIRST (oldest in the vmcnt FIFO): their consumer
        //    wait is then vmcnt(3), leaving next-stage loads in flight.
        const float* p = (inX ? xr : hr) + kk;
        float a8[8];
        *(float4*)&a8[0] = *(const float4*)(p);
        *(float4*)&a8[4] = *(const float4*)(p + 4);
        __builtin_amdgcn_sched_barrier(0);     // pin: acts issue before stage

        // 2) next chunk's weight staging (completes by the next barrier)
        if (kc + 32 < KT) stage(kc + 32, cur ^ 1);

        // 3) split3 + MFMA stream (unchanged)
        bfrag8 bh, bm, bl;
#pragma unroll
        for (int j = 0; j < 8; ++j) {
            unsigned short h, m, l;
            split3(a8[j], h, m, l);
            bh[j] = (short)h; bm[j] = (short)m; bl[j] = (short)l;
        }

        const unsigned short* bufp = wlds[cur];
#pragma unroll
        for (int hh = 0; hh < 2; ++hh) {
            bfrag8 ah[4], am4[4], al[4];
#pragma unroll
            for (int t = 0; t < 4; ++t) {
                const int tn = hh * 4 + t;
                ah[t]  = *(const bfrag8*)(bufp + boffW[tn]);
                am4[t] = *(const bfrag8*)(bufp + 4096 + boffW[tn]);
                al[t]  = *(const bfrag8*)(bufp + 8192 + boffW[tn]);
            }
#pragma unroll
            for (int t = 0; t < 4; ++t) {
                const int tn = hh * 4 + t;
                f32x4 c = acc[tn];
                c = __builtin_amdgcn_mfma_f32_16x16x32_bf16(ah[t], bl, c, 0, 0, 0);
                c = __builtin_amdgcn_mfma_f32_16x16x32_bf16(al[t], bh, c, 0, 0, 0);
                c = __builtin_amdgcn_mfma_f32_16x16x32_bf16(am4[t], bm, c, 0, 0, 0);
                c = __builtin_amdgcn_mfma_f32_16x16x32_bf16(ah[t], bm, c, 0, 0, 0);
                c = __builtin_amdgcn_mfma_f32_16x16x32_bf16(am4[t], bh, c, 0, 0, 0);
                c = __builtin_amdgcn_mfma_f32_16x16x32_bf16(ah[t], bh, c, 0, 0, 0);
                acc[tn] = c;
            }
        }
        cur ^= 1;
    }

    // ---- coalesced epilogue: wlds reused as [128][33] f32 bounce buffers --
    __syncthreads();                 // all waves done reading wlds
    float* hs = (float*)&wlds[0][0];             // [128][33]
    float* cs = hs + 128 * 33;                   // [128][33] (33.8 KB total)

    const int er = tid >> 2;                     // bounce row 0..127
    const int ec = (tid & 3) * 8;                // bounce col 0,8,16,24
    const size_t gbase = (size_t)(mB0 + er) * Hdim + (c0 >> 2) + ec;

    // phase 0: coalesced c_in tile load -> cs
    if (!czero) {
        float4 ci0 = *(const float4*)(c_in + gbase);
        float4 ci1 = *(const float4*)(c_in + gbase + 4);
        float* dst = cs + er * 33 + ec;
        dst[0] = ci0.x; dst[1] = ci0.y; dst[2] = ci0.z; dst[3] = ci0.w;
        dst[4] = ci1.x; dst[5] = ci1.y; dst[6] = ci1.z; dst[7] = ci1.w;
    }
    __syncthreads();

    // phase 1: gate math (identical FP ops), scatter to LDS
    const int lr = wv * 16 + lm;                 // this lane's local row
#pragma unroll
    for (int tn = 0; tn < 8; ++tn) {
        const int nb = c0 + tn * 16 + quad * 4;
        float4 bb = *(const float4*)(biasI + nb);
        const int jl = tn * 4 + quad;            // local col 0..31
        float gi = acc[tn][0] + bb.x;
        float gf = acc[tn][1] + bb.y;
        float gg = acc[tn][2] + bb.z;
        float go = acc[tn][3] + bb.w;
        float si = 1.f / (1.f + expf(-gi));
        float sf = 1.f / (1.f + expf(-gf));
        float so = 1.f / (1.f + expf(-go));
        float co = czero ? 0.f : cs[lr * 33 + jl];
        float cn = si * tanhf(gg) + sf * co;
        cs[lr * 33 + jl] = cn;
        hs[lr * 33 + jl] = so * tanhf(cn);
    }
    __syncthreads();

    // phase 2: coalesced float4 stores (32B/thread, full 128B row segments)
    {
        const float* hsrc = hs + er * 33 + ec;
        const float* csrc = cs + er * 33 + ec;
        float4 h0v, h1v, c0v, c1v;
        h0v.x = hsrc[0]; h0v.y = hsrc[1]; h0v.z = hsrc[2]; h0v.w = hsrc[3];
        h1v.x = hsrc[4]; h1v.y = hsrc[5]; h1v.z = hsrc[6]; h1v.w = hsrc[7];
        c0v.x = csrc[0]; c0v.y = csrc[1]; c0v.z = csrc[2]; c0v.w = csrc[3];
        c1v.x = csrc[4]; c1v.y = csrc[5]; c1v.z = csrc[6]; c1v.w = csrc[7];
        *(float4*)(h_out + gbase)     = h0v;
        *(float4*)(h_out + gbase + 4) = h1v;
        *(float4*)(c_out + gbase)     = c0v;
        *(float4*)(c_out + gbase + 4) = c1v;
    }
}

// ---------------------------------------------------------------------------
// MFMA projection GEMM: C[m] = A[m] @ W^T + bias (W via bf16x6 planes,
// K=512). 64m x 64n block, 4 waves (wave = 16m x 64n, acc 4x1), grid
// (64,8)=512, dual LDS double-buffer staging with both-sides swizzles.
// (round-11 body, verbatim)
// ---------------------------------------------------------------------------
__global__ __launch_bounds__(256) void proj_mfma(
    const unsigned short* __restrict__ Wh, const unsigned short* __restrict__ Wm,
    const unsigned short* __restrict__ Wl,
    const float* __restrict__ A,
    const float* __restrict__ bias,
    float* __restrict__ C, int ldc)
{
    __shared__ __align__(16) unsigned short wlds[2][3 * 2048]; // 24 KB
    __shared__ __align__(16) float alds[2][64 * 32];           // 16 KB

    const int tid = threadIdx.x;
    const int wv = tid >> 6, lane = tid & 63;
    const int lm = lane & 15, quad = lane >> 4;
    const int nB0 = blockIdx.y * 64;             // output-channel panel base
    const int mB0 = blockIdx.x * 64;             // batch tile base

    // ---- weight staging: 64 rows x 4 x 16B units, 256 threads, 1 issue ----
    const int rw = tid >> 2;                               // row 0..63
    const int sqw = (tid & 3) ^ ((rw >> 1) & 3);           // swizzled src unit
    const size_t wroff = (size_t)(nB0 + rw) * Hdim + (size_t)(sqw * 8);

    // ---- act staging: 2 issues x 32 rows x 8 x 16B units ----
    const int asw = ((lane & 7) ^ (lane >> 3)) * 4;        // swizzled src floats
    const float* asrc[2];
#pragma unroll
    for (int i = 0; i < 2; ++i) {
        const int r = i * 32 + wv * 8 + (lane >> 3);
        asrc[i] = A + (size_t)(mB0 + r) * Hdim + asw;
    }

    // ---- ds_read offsets ----
    int boffW[4];
#pragma unroll
    for (int tn = 0; tn < 4; ++tn) {
        const int r = tn * 16 + lm;
        boffW[tn] = r * 32 + ((quad ^ ((r >> 1) & 3)) * 8);
    }
    const int ra = wv * 16 + lm;                           // wave's act row
    const int boffA1 = ra * 32 + (((2 * quad)     ^ (lm & 7)) << 2);
    const int boffA2 = ra * 32 + (((2 * quad + 1) ^ (lm & 7)) << 2);

    auto stage = [&](int kb, int buf) {
        unsigned short* lb0 = &wlds[buf][wv * 512];
        __builtin_amdgcn_global_load_lds(
            (const __attribute__((address_space(1))) void*)(Wh + wroff + kb),
            (__attribute__((address_space(3))) void*)(lb0), 16, 0, 0);
        __builtin_amdgcn_global_load_lds(
            (const __attribute__((address_space(1))) void*)(Wm + wroff + kb),
            (__attribute__((address_space(3))) void*)(lb0 + 2048), 16, 0, 0);
        __builtin_amdgcn_global_load_lds(
            (const __attribute__((address_space(1))) void*)(Wl + wroff + kb),
            (__attribute__((address_space(3))) void*)(lb0 + 4096), 16, 0, 0);
#pragma unroll
        for (int i = 0; i < 2; ++i) {
            float* lb = &alds[buf][(i * 32 + wv * 8) * 32];
            __builtin_amdgcn_global_load_lds(
                (const __attribute__((address_space(1))) void*)(asrc[i] + kb),
                (__attribute__((address_space(3))) void*)lb, 16, 0, 0);
        }
    };

    f32x4 acc[4];
#pragma unroll
    for (int i = 0; i < 4; ++i) acc[i] = (f32x4){0.f, 0.f, 0.f, 0.f};

    stage(0, 0);
    int cur = 0;

    for (int kc = 0; kc < Hdim; kc += 32) {
        __syncthreads();
        if (kc + 32 < Hdim) stage(kc + 32, cur ^ 1);

        const float* abuf = alds[cur];
        float a8[8];
        *(float4*)&a8[0] = *(const float4*)(abuf + boffA1);
        *(float4*)&a8[4] = *(const float4*)(abuf + boffA2);
        bfrag8 bh, bm, bl;
#pragma unroll
        for (int j = 0; j < 8; ++j) {
            unsigned short h, m, l;
            split3(a8[j], h, m, l);
            bh[j] = (short)h; bm[j] = (short)m; bl[j] = (short)l;
        }

        const unsigned short* bufp = wlds[cur];
#pragma unroll
        for (int tn = 0; tn < 4; ++tn) {
            bfrag8 ah  = *(const bfrag8*)(bufp + boffW[tn]);
            bfrag8 am4 = *(const bfrag8*)(bufp + 2048 + boffW[tn]);
            bfrag8 al  = *(const bfrag8*)(bufp + 4096 + boffW[tn]);
            f32x4 c = acc[tn];
            c = __builtin_amdgcn_mfma_f32_16x16x32_bf16(ah,  bl, c, 0, 0, 0);
            c = __builtin_amdgcn_mfma_f32_16x16x32_bf16(al,  bh, c, 0, 0, 0);
            c = __builtin_amdgcn_mfma_f32_16x16x32_bf16(am4, bm, c, 0, 0, 0);
            c = __builtin_amdgcn_mfma_f32_16x16x32_bf16(ah,  bm, c, 0, 0, 0);
            c = __builtin_amdgcn_mfma_f32_16x16x32_bf16(am4, bh, c, 0, 0, 0);
            c = __builtin_amdgcn_mfma_f32_16x16x32_bf16(ah,  bh, c, 0, 0, 0);
            acc[tn] = c;
        }
        cur ^= 1;
    }

    // epilogue: lane reg r of acc[tn] = channel nB0+tn*16+quad*4+r, batch
    // row mB0+wv*16+lm (planes NOT gate-interleaved).
    const int m = mB0 + wv * 16 + lm;
#pragma unroll
    for (int tn = 0; tn < 4; ++tn) {
        const int n = nB0 + tn * 16 + quad * 4;
        float4 bb = *(const float4*)(bias + n);
        float4 o;
        o.x = acc[tn][0] + bb.x;
        o.y = acc[tn][1] + bb.y;
        o.z = acc[tn][2] + bb.z;
        o.w = acc[tn][3] + bb.w;
        *(float4*)(C + (size_t)m * ldc + n) = o;
    }
}

// ---------------------------------------------------------------------------
// Attention + log-softmax + argmax + state update. u2 layout [s][b][h].
// ---------------------------------------------------------------------------
__global__ __launch_bounds__(256) void attn_step(const float* __restrict__ qp,
                                                 const float* __restrict__ u2,
                                                 const float* __restrict__ Vec2,
                                                 float* __restrict__ mask,
                                                 float* __restrict__ ll_ws,
                                                 int* __restrict__ nxt,
                                                 float* __restrict__ out_map,
                                                 float* __restrict__ out_ll,
                                                 int step, int node) {
    const int b = blockIdx.x;
    __shared__ float qpS[Hdim];
    __shared__ float vS[Hdim];
    __shared__ float logitS[Sseq];
    const int tid = threadIdx.x;
    qpS[tid]       = qp[(size_t)b * Hdim + tid];
    qpS[tid + 256] = qp[(size_t)b * Hdim + 256 + tid];
    vS[tid]        = Vec2[tid];
    vS[tid + 256]  = Vec2[256 + tid];
    __syncthreads();

    const int wave = tid >> 6, lane = tid & 63;
    for (int si = 0; si < 4; ++si) {
        int s = wave * 4 + si;
        const float* u2p = u2 + ((size_t)s * Bsz + b) * Hdim;   // [s][b][h]
        float sum = 0.f;
#pragma unroll
        for (int i = 0; i < 8; ++i) {
            int hh = lane + i * 64;
            sum += vS[hh] * tanhf(qpS[hh] + u2p[hh]);
        }
        for (int off = 32; off > 0; off >>= 1) sum += __shfl_down(sum, off);
        if (lane == 0) {
            float pen = step ? mask[b * Sseq + s] * 1e8f : 0.f;
            logitS[s] = 10.f * sum - pen;
        }
    }
    __syncthreads();

    if (tid == 0) {
        float mx = logitS[0];
        int am = 0;
        for (int s = 1; s < Sseq; ++s)
            if (logitS[s] > mx) { mx = logitS[s]; am = s; }
        float se = 0.f;
        for (int s = 0; s < Sseq; ++s) se += expf(logitS[s] - mx);
        float lp = -logf(se);
        float llv = (step ? ll_ws[b] : 0.f) + lp;
        ll_ws[b] = llv;
        out_ll[b] = llv;
        nxt[b] = am;
        if (step == 0) {
            for (int s = 0; s < Sseq; ++s) mask[b * Sseq + s] = (s == am) ? 1.f : 0.f;
        } else {
            mask[b * Sseq + am] += 1.f;
        }
        out_map[b * Sseq + am] = (float)node;
    }
}

// ---------------------------------------------------------------------------
extern "C" void kernel_launch(void* const* d_in, const int* in_sizes, int n_in,
                              void* d_out, int out_size, void* d_ws, size_t ws_size,
                              hipStream_t stream) {
    const float* x       = (const float*)d_in[0];
    const float* emb_W   = (const float*)d_in[1];
    const float* enc_Wih = (const float*)d_in[2];
    const float* enc_Whh = (const float*)d_in[3];
    const float* enc_b   = (const float*)d_in[4];
    const float* dec_Wih = (const float*)d_in[5];
    const float* dec_Whh = (const float*)d_in[6];
    const float* dec_b   = (const float*)d_in[7];
    const float* Wq2     = (const float*)d_in[8];
    const float* bq2     = (const float*)d_in[9];
    const float* Wref2   = (const float*)d_in[10];
    const float* bref2   = (const float*)d_in[11];
    const float* Vec2    = (const float*)d_in[12];
    const float* dec0    = (const float*)d_in[13];

    const size_t BH = (size_t)Bsz * Hdim;

    // workspace layout — ~195 MB
    float* ws      = (float*)d_ws;
    float* u2      = ws;                                   // S*B*H fp32 ([s][b][h])
    float* h0      = u2 + (size_t)Bsz * Sseq * Hdim;       // B*H each
    float* c0      = h0 + BH;
    float* h1      = c0 + BH;
    float* c1      = h1 + BH;
    float* qp      = c1 + BH;
    float* mask    = qp + BH;                              // B*S
    float* ll      = mask + (size_t)Bsz * Sseq;            // B
    int*   nxt     = (int*)(ll + Bsz);                     // B
    float* encBI   = (float*)(nxt + Bsz);                  // 2048 each
    float* decBI   = encBI + H4;
    float* v0bI    = decBI + H4;
    // bf16 weight planes (ushort)
    unsigned short* us = (unsigned short*)(v0bI + H4);
    unsigned short* encEh = us;                       us += (size_t)H4 * Gdim;
    unsigned short* encEm = us;                       us += (size_t)H4 * Gdim;
    unsigned short* encEl = us;                       us += (size_t)H4 * Gdim;
    unsigned short* encWh = us;                       us += (size_t)H4 * Hdim;
    unsigned short* encWm = us;                       us += (size_t)H4 * Hdim;
    unsigned short* encWl = us;                       us += (size_t)H4 * Hdim;
    unsigned short* decEh = us;                       us += (size_t)H4 * Gdim;
    unsigned short* decEm = us;                       us += (size_t)H4 * Gdim;
    unsigned short* decEl = us;                       us += (size_t)H4 * Gdim;
    unsigned short* decWh = us;                       us += (size_t)H4 * Hdim;
    unsigned short* decWm = us;                       us += (size_t)H4 * Hdim;
    unsigned short* decWl = us;                       us += (size_t)H4 * Hdim;
    // projection weight planes (512x512 each)
    unsigned short* prWh = us;                        us += (size_t)Hdim * Hdim;
    unsigned short* prWm = us;                        us += (size_t)Hdim * Hdim;
    unsigned short* prWl = us;                        us += (size_t)Hdim * Hdim;
    unsigned short* pqWh = us;                        us += (size_t)Hdim * Hdim;
    unsigned short* pqWm = us;                        us += (size_t)Hdim * Hdim;
    unsigned short* pqWl = us;                        us += (size_t)Hdim * Hdim;

    float* out_map = (float*)d_out;                        // B*P floats
    float* out_ll  = out_map + (size_t)Bsz * Psteps;       // B floats

    static const int nodes[Psteps] = {0,0,0,0, 1,1,1,1, 2,2,2,2, 3,3,3,3};

    fold_kernel<<<H4, Gdim, 0, stream>>>(enc_Wih, enc_Whh, enc_b,
                                         dec_Wih, dec_Whh, dec_b,
                                         emb_W, dec0,
                                         encEh, encEm, encEl, encWh, encWm, encWl,
                                         decEh, decEm, decEl, decWh, decWm, decWl,
                                         encBI, decBI, v0bI);
    fold_proj<<<dim3(Hdim, 2), 256, 0, stream>>>(Wref2, Wq2,
                                                 prWh, prWm, prWl,
                                                 pqWh, pqWm, pqWl);

    const dim3 gBig(32, 16);    // gates grid: 512 blocks (512 thr), 48KB LDS
    const dim3 gPr(64, 8);      // proj grid:  512 blocks = 2/CU

    // ---- encoder: 16 fused LSTM steps + u2[t] projection of h(t) ----
    for (int t = 0; t < Sseq; ++t) {
        float* ho = (t & 1) ? h0 : h1;
        float* co = (t & 1) ? c0 : c1;
        const float* hi = (t & 1) ? h1 : h0;
        const float* ci = (t & 1) ? c1 : c0;
        if (t == 0) {
            gates_mfma<<<gBig, 512, 0, stream>>>(
                encEh, encEm, encEl, Gdim,
                x, Sseq * Gdim, nullptr, 0,
                nullptr, nullptr, nullptr, 0, nullptr,
                encBI, ci, ho, co, 1);
        } else {
            gates_mfma<<<gBig, 512, 0, stream>>>(
                encEh, encEm, encEl, Gdim,
                x + t * Gdim, Sseq * Gdim, nullptr, 0,
                encWh, encWm, encWl, Hdim, hi,
                encBI, ci, ho, co, 0);
        }
        // u2[t] projection into [s][b][h] layout
        proj_mfma<<<gPr, 256, 0, stream>>>(prWh, prWm, prWl, ho, bref2,
                                           u2 + (size_t)t * BH, Hdim);
    }

    // ---- decoder: 16 autoregressive steps ----
    for (int p = 0; p < Psteps; ++p) {
        const int u = Sseq + p;
        float* ho = (u & 1) ? h0 : h1;
        float* co = (u & 1) ? c0 : c1;
        const float* hi = (u & 1) ? h1 : h0;
        const float* ci = (u & 1) ? c1 : c0;
        if (p == 0) {
            gates_mfma<<<gBig, 512, 0, stream>>>(
                nullptr, nullptr, nullptr, 0,
                nullptr, 0, nullptr, 0,
                decWh, decWm, decWl, Hdim, hi,
                v0bI, ci, ho, co, 0);
        } else {
            gates_mfma<<<gBig, 512, 0, stream>>>(
                decEh, decEm, decEl, Gdim,
                x, Sseq * Gdim, nxt, Gdim,
                decWh, decWm, decWl, Hdim, hi,
                decBI, ci, ho, co, 0);
        }
        proj_mfma<<<gPr, 256, 0, stream>>>(pqWh, pqWm, pqWl, ho, bq2,
                                           qp, Hdim);
        attn_step<<<Bsz, 256, 0, stream>>>(qp, u2, Vec2, mask, ll, nxt,
                                           out_map, out_ll, p, nodes[p]);
    }
}